// Round 1
// baseline (713.591 us; speedup 1.0000x reference)
//
#include <hip/hip_runtime.h>
#include <hip/hip_bf16.h>

typedef _Float16 f16;
typedef f16 f16x2 __attribute__((ext_vector_type(2)));
typedef f16 f16x4 __attribute__((ext_vector_type(4)));
typedef f16 f16x8 __attribute__((ext_vector_type(8)));
typedef float f32x4 __attribute__((ext_vector_type(4)));
typedef float f32x16 __attribute__((ext_vector_type(16)));

#define SEQ 512
#define DIM 64
#define NBH 96
#define OUT0 3145728          // 8*12*512*64
#define PSZ  25165824         // 8*12*512*512
#define MSZ  262144           // 512*512

__device__ __forceinline__ int swz(int row, int colByte) {
    return row * 128 + (colByte ^ ((row & 7) << 4));
}

// ---------------- scores + masked softmax (5 matrices) ----------------
__global__ __launch_bounds__(256) void scores_softmax(
    const float* __restrict__ q_, const float* __restrict__ k_,
    const float* __restrict__ xo1, const float* __restrict__ xo2,
    const float* __restrict__ xp1, const float* __restrict__ xp2,
    const int* __restrict__ mask, float* __restrict__ dout)
{
    __shared__ __align__(16) f16 As[32 * 64];
    __shared__ __align__(16) f16 Bs[128 * 64];
    __shared__ float red[4][32];

    const int tid = threadIdx.x;
    const int bid = blockIdx.x;
    const int qt  = bid & 15;
    const int bhm = bid >> 4;
    const int bh  = bhm % NBH;
    const int m   = bhm / NBH;

    const float* Ap; const float* Bp;
    if      (m == 0) { Ap = q_;  Bp = k_;  }
    else if (m == 1) { Ap = xo1; Bp = xo2; }
    else if (m == 2) { Ap = xo1; Bp = xp2; }
    else if (m == 3) { Ap = xp1; Bp = xo2; }
    else             { Ap = xp1; Bp = xp2; }

    const int w = tid >> 6, lane = tid & 63, l31 = lane & 31, half = lane >> 5;

    // stage A tile [32 q][64 d] -> f16 LDS (swizzled)
    const float* Ag = Ap + ((size_t)bh * SEQ + qt * 32) * DIM;
#pragma unroll
    for (int i = 0; i < 2; i++) {
        int g = tid + 256 * i; int row = g >> 4, c4 = g & 15;
        f32x4 v = *reinterpret_cast<const f32x4*>(Ag + row * 64 + c4 * 4);
        f16x4 b; b[0]=(f16)v[0]; b[1]=(f16)v[1]; b[2]=(f16)v[2]; b[3]=(f16)v[3];
        *reinterpret_cast<f16x4*>((char*)As + swz(row, c4 * 8)) = b;
    }
    __syncthreads();

    f16x8 afr[4];
#pragma unroll
    for (int k4 = 0; k4 < 4; k4++)
        afr[k4] = *reinterpret_cast<const f16x8*>((char*)As + swz(l31, k4 * 32 + half * 16));

    f32x16 acc[4];
#pragma unroll
    for (int c = 0; c < 4; c++)
#pragma unroll
        for (int i = 0; i < 16; i++) acc[c][i] = 0.f;

    const float* Bg0 = Bp + (size_t)bh * SEQ * DIM;
    for (int c = 0; c < 4; c++) {
        __syncthreads();
        const float* Bg = Bg0 + (size_t)c * 128 * DIM;
#pragma unroll
        for (int i = 0; i < 8; i++) {
            int g = tid + 256 * i; int row = g >> 4, c4 = g & 15;
            f32x4 v = *reinterpret_cast<const f32x4*>(Bg + row * 64 + c4 * 4);
            f16x4 b; b[0]=(f16)v[0]; b[1]=(f16)v[1]; b[2]=(f16)v[2]; b[3]=(f16)v[3];
            *reinterpret_cast<f16x4*>((char*)Bs + swz(row, c4 * 8)) = b;
        }
        __syncthreads();
        int rb = w * 32 + l31;
#pragma unroll
        for (int k4 = 0; k4 < 4; k4++) {
            f16x8 bfr = *reinterpret_cast<const f16x8*>((char*)Bs + swz(rb, k4 * 32 + half * 16));
            acc[c] = __builtin_amdgcn_mfma_f32_32x32x16_f16(afr[k4], bfr, acc[c], 0, 0, 0);
        }
    }

    // epilogue: mask, exp (no max needed: scores bounded, masked -> exactly 0)
    const int b = bh / 12;
    const int* mrow = mask + (size_t)b * MSZ + (size_t)(qt * 32) * SEQ;
    float rsum[16];
#pragma unroll
    for (int r = 0; r < 16; r++) rsum[r] = 0.f;
#pragma unroll
    for (int c = 0; c < 4; c++) {
        int kcol = c * 128 + w * 32 + l31;
#pragma unroll
        for (int r = 0; r < 16; r++) {
            int qrow = (r & 3) + 8 * (r >> 2) + 4 * half;
            int mk = mrow[(size_t)qrow * SEQ + kcol];
            float e = mk ? __expf(acc[c][r] * 0.125f) : 0.f;
            acc[c][r] = e;
            rsum[r] += e;
        }
    }
    // row-sum: tree within 32-lane half (rows are half-local), then cross-wave via LDS
#pragma unroll
    for (int d = 1; d < 32; d <<= 1)
#pragma unroll
        for (int r = 0; r < 16; r++) rsum[r] += __shfl_xor(rsum[r], d);
    if (l31 == 0) {
#pragma unroll
        for (int r = 0; r < 16; r++) {
            int qrow = (r & 3) + 8 * (r >> 2) + 4 * half;
            red[w][qrow] = rsum[r];
        }
    }
    __syncthreads();
    float inv[16];
#pragma unroll
    for (int r = 0; r < 16; r++) {
        int qrow = (r & 3) + 8 * (r >> 2) + 4 * half;
        float s = red[0][qrow] + red[1][qrow] + red[2][qrow] + red[3][qrow];
        inv[r] = 1.0f / s;
    }
    float* P = dout + OUT0 + (size_t)m * PSZ + (size_t)bh * MSZ + (size_t)(qt * 32) * SEQ;
#pragma unroll
    for (int c = 0; c < 4; c++) {
        int kcol = c * 128 + w * 32 + l31;
#pragma unroll
        for (int r = 0; r < 16; r++) {
            int qrow = (r & 3) + 8 * (r >> 2) + 4 * half;
            P[(size_t)qrow * SEQ + kcol] = acc[c][r] * inv[r];
        }
    }
}

// ---------------- V transpose: [bh][k][d] fp32 -> [bh][d][k] f16 ----------------
__global__ __launch_bounds__(256) void vtrans(const float* __restrict__ v, f16* __restrict__ vt)
{
    __shared__ float t[128][65];
    const int tid = threadIdx.x;
    const int bh = blockIdx.x >> 2, ck = blockIdx.x & 3;
    const float* Vg = v + ((size_t)bh * SEQ + ck * 128) * DIM;
#pragma unroll
    for (int i = 0; i < 8; i++) {
        int g = tid + 256 * i; int row = g >> 4, c4 = g & 15;
        f32x4 vv = *reinterpret_cast<const f32x4*>(Vg + row * 64 + c4 * 4);
        t[row][c4*4+0] = vv[0]; t[row][c4*4+1] = vv[1];
        t[row][c4*4+2] = vv[2]; t[row][c4*4+3] = vv[3];
    }
    __syncthreads();
    f16* Og = vt + (size_t)bh * DIM * SEQ + ck * 128;
#pragma unroll
    for (int i = 0; i < 16; i++) {
        int p = tid + 256 * i; int d = p >> 6; int j = (p & 63) * 2;
        f16x2 o; o[0] = (f16)t[j][d]; o[1] = (f16)t[j + 1][d];
        *reinterpret_cast<f16x2*>(Og + (size_t)d * SEQ + j) = o;
    }
}

// ---------------- PV via MFMA (reads p_attn from dout, Vt from ws) ----------------
__global__ __launch_bounds__(256) void pv_mfma(const float* __restrict__ dout,
                                               const f16* __restrict__ vt,
                                               float* __restrict__ out)
{
    __shared__ __align__(16) f16 Ps[64 * 64];
    __shared__ __align__(16) f16 Vs[64 * 64];
    const int tid = threadIdx.x;
    const int bh = blockIdx.x >> 3, qt = blockIdx.x & 7;
    const int w = tid >> 6, lane = tid & 63, l31 = lane & 31, half = lane >> 5;
    const int wr = w >> 1, wc = w & 1;

    const float* Pg = dout + OUT0 + (size_t)bh * MSZ + (size_t)(qt * 64) * SEQ;
    const f16* Vg = vt + (size_t)bh * DIM * SEQ;

    f32x16 acc;
#pragma unroll
    for (int i = 0; i < 16; i++) acc[i] = 0.f;

    for (int c = 0; c < 8; c++) {
        __syncthreads();
#pragma unroll
        for (int i = 0; i < 4; i++) {            // P chunk [64 q][64 kv]
            int g = tid + 256 * i; int row = g >> 4, c4 = g & 15;
            f32x4 v = *reinterpret_cast<const f32x4*>(Pg + (size_t)row * SEQ + c * 64 + c4 * 4);
            f16x4 b; b[0]=(f16)v[0]; b[1]=(f16)v[1]; b[2]=(f16)v[2]; b[3]=(f16)v[3];
            *reinterpret_cast<f16x4*>((char*)Ps + swz(row, c4 * 8)) = b;
        }
#pragma unroll
        for (int i = 0; i < 2; i++) {            // Vt chunk [64 d][64 kv]
            int g = tid + 256 * i; int row = g >> 3, c8 = g & 7;
            f16x8 v = *reinterpret_cast<const f16x8*>(Vg + (size_t)row * SEQ + c * 64 + c8 * 8);
            *reinterpret_cast<f16x8*>((char*)Vs + swz(row, c8 * 16)) = v;
        }
        __syncthreads();
        int qr = wr * 32 + l31, dr = wc * 32 + l31;
#pragma unroll
        for (int k4 = 0; k4 < 4; k4++) {
            int co = k4 * 32 + half * 16;
            f16x8 a  = *reinterpret_cast<const f16x8*>((char*)Ps + swz(qr, co));
            f16x8 bb = *reinterpret_cast<const f16x8*>((char*)Vs + swz(dr, co));
            acc = __builtin_amdgcn_mfma_f32_32x32x16_f16(a, bb, acc, 0, 0, 0);
        }
    }
    float* og = out + ((size_t)bh * SEQ + qt * 64 + wr * 32) * DIM + wc * 32;
#pragma unroll
    for (int r = 0; r < 16; r++) {
        int qrow = (r & 3) + 8 * (r >> 2) + 4 * half;
        og[(size_t)qrow * DIM + l31] = acc[r];
    }
}

// ---------------- PV vector fallback (if ws too small for Vt) ----------------
__global__ __launch_bounds__(256) void pv_vec(const float* __restrict__ dout,
                                              const float* __restrict__ v,
                                              float* __restrict__ out)
{
    __shared__ float Vs[128][64];
    const int tid = threadIdx.x;
    const int bh = blockIdx.x >> 3, qt = blockIdx.x & 7;
    float accv[16];
#pragma unroll
    for (int j = 0; j < 16; j++) accv[j] = 0.f;
    const float* Prow = dout + OUT0 + ((size_t)bh * SEQ + qt * 64 + (tid >> 2)) * SEQ;
    const int dbase = (tid & 3) * 16;
    for (int ck = 0; ck < 4; ck++) {
        __syncthreads();
        const float* Vg = v + ((size_t)bh * SEQ + ck * 128) * DIM;
#pragma unroll
        for (int i = 0; i < 8; i++) {
            int g = tid + 256 * i; int row = g >> 4, c4 = g & 15;
            f32x4 vv = *reinterpret_cast<const f32x4*>(Vg + row * 64 + c4 * 4);
            Vs[row][c4*4+0] = vv[0]; Vs[row][c4*4+1] = vv[1];
            Vs[row][c4*4+2] = vv[2]; Vs[row][c4*4+3] = vv[3];
        }
        __syncthreads();
        for (int kv = 0; kv < 128; kv++) {
            float p = Prow[ck * 128 + kv];
#pragma unroll
            for (int j = 0; j < 16; j++) accv[j] += p * Vs[kv][dbase + j];
        }
    }
    float* og = out + ((size_t)bh * SEQ + qt * 64 + (tid >> 2)) * DIM + dbase;
#pragma unroll
    for (int j = 0; j < 16; j++) og[j] = accv[j];
}

extern "C" void kernel_launch(void* const* d_in, const int* in_sizes, int n_in,
                              void* d_out, int out_size, void* d_ws, size_t ws_size,
                              hipStream_t stream) {
    const float* q_  = (const float*)d_in[0];
    const float* k_  = (const float*)d_in[1];
    const float* v_  = (const float*)d_in[2];
    const int*   msk = (const int*)d_in[3];
    const float* xo1 = (const float*)d_in[4];
    const float* xo2 = (const float*)d_in[5];
    const float* xp1 = (const float*)d_in[6];
    const float* xp2 = (const float*)d_in[7];
    float* out = (float*)d_out;

    scores_softmax<<<5 * NBH * 16, 256, 0, stream>>>(q_, k_, xo1, xo2, xp1, xp2, msk, out);

    const size_t need = (size_t)NBH * DIM * SEQ * sizeof(f16);
    if (ws_size >= need) {
        f16* vt = (f16*)d_ws;
        vtrans<<<NBH * 4, 256, 0, stream>>>(v_, vt);
        pv_mfma<<<NBH * 8, 256, 0, stream>>>(out, vt, out);
    } else {
        pv_vec<<<NBH * 8, 256, 0, stream>>>(out, v_, out);
    }
}

// Round 4
// 688.825 us; speedup vs baseline: 1.0360x; 1.0360x over previous
//
#include <hip/hip_runtime.h>
#include <hip/hip_bf16.h>

typedef _Float16 f16;
typedef f16 f16x2 __attribute__((ext_vector_type(2)));
typedef f16 f16x4 __attribute__((ext_vector_type(4)));
typedef f16 f16x8 __attribute__((ext_vector_type(8)));
typedef float f32x4 __attribute__((ext_vector_type(4)));
typedef float f32x16 __attribute__((ext_vector_type(16)));
typedef int i32x4 __attribute__((ext_vector_type(4)));
typedef unsigned char u8;
typedef u8 u8x4 __attribute__((ext_vector_type(4)));

#define SEQ 512
#define DIM 64
#define NBH 96
#define OUT0 3145728          // 8*12*512*64
#define PSZ  25165824         // 8*12*512*512
#define MSZ  262144           // 512*512

__device__ __forceinline__ int swz(int row, int colByte) {
    return row * 128 + (colByte ^ ((row & 7) << 4));
}

// ---------------- scores + masked softmax (5 matrices) ----------------
// Grid 7680; b = bid&7 -> batch pinned to XCD (L2 locality for mask + B panels).
__global__ __launch_bounds__(256) void scores_softmax(
    const float* __restrict__ q_, const float* __restrict__ k_,
    const float* __restrict__ xo1, const float* __restrict__ xo2,
    const float* __restrict__ xp1, const float* __restrict__ xp2,
    const int* __restrict__ mask, float* __restrict__ dout)
{
    __shared__ __align__(16) f16 As[32 * 64];
    __shared__ __align__(16) f16 Bs[128 * 64];
    __shared__ __align__(16) u8  Ms[32 * 512];
    __shared__ float red[4][32];

    const int tid = threadIdx.x;
    const int bid = blockIdx.x;
    const int b   = bid & 7;          // XCD-local batch
    int t = bid >> 3;                 // 0..959
    const int qt = t & 15;
    t >>= 4;                          // 0..59
    const int h  = t % 12;
    const int m  = t / 12;
    const int bh = b * 12 + h;

    const float* Ap; const float* Bp;
    if      (m == 0) { Ap = q_;  Bp = k_;  }
    else if (m == 1) { Ap = xo1; Bp = xo2; }
    else if (m == 2) { Ap = xo1; Bp = xp2; }
    else if (m == 3) { Ap = xp1; Bp = xo2; }
    else             { Ap = xp1; Bp = xp2; }

    const int w = tid >> 6, lane = tid & 63, l31 = lane & 31, half = lane >> 5;

    // stage mask tile [32 q][512 k] -> u8 LDS (16 int4 loads/thread)
    const int* mrow = mask + (size_t)b * MSZ + (size_t)(qt * 32) * SEQ;
#pragma unroll
    for (int i = 0; i < 16; i++) {
        int g = tid + 256 * i;        // int4 index, 0..4095
        i32x4 mv = *reinterpret_cast<const i32x4*>(mrow + g * 4);
        u8x4 pk;
        pk[0] = (u8)(mv[0] != 0); pk[1] = (u8)(mv[1] != 0);
        pk[2] = (u8)(mv[2] != 0); pk[3] = (u8)(mv[3] != 0);
        *reinterpret_cast<u8x4*>(&Ms[g * 4]) = pk;
    }

    // stage A tile [32 q][64 d] -> f16 LDS (swizzled)
    const float* Ag = Ap + ((size_t)bh * SEQ + qt * 32) * DIM;
#pragma unroll
    for (int i = 0; i < 2; i++) {
        int g = tid + 256 * i; int row = g >> 4, c4 = g & 15;
        f32x4 v = *reinterpret_cast<const f32x4*>(Ag + row * 64 + c4 * 4);
        f16x4 bb; bb[0]=(f16)v[0]; bb[1]=(f16)v[1]; bb[2]=(f16)v[2]; bb[3]=(f16)v[3];
        *reinterpret_cast<f16x4*>((char*)As + swz(row, c4 * 8)) = bb;
    }
    __syncthreads();

    f16x8 afr[4];
#pragma unroll
    for (int k4 = 0; k4 < 4; k4++)
        afr[k4] = *reinterpret_cast<const f16x8*>((char*)As + swz(l31, k4 * 32 + half * 16));

    f32x16 acc[4];
#pragma unroll
    for (int c = 0; c < 4; c++)
#pragma unroll
        for (int i = 0; i < 16; i++) acc[c][i] = 0.f;

    const float* Bg0 = Bp + (size_t)bh * SEQ * DIM;
    for (int c = 0; c < 4; c++) {
        __syncthreads();
        const float* Bg = Bg0 + (size_t)c * 128 * DIM;
#pragma unroll
        for (int i = 0; i < 8; i++) {
            int g = tid + 256 * i; int row = g >> 4, c4 = g & 15;
            f32x4 v = *reinterpret_cast<const f32x4*>(Bg + row * 64 + c4 * 4);
            f16x4 bb; bb[0]=(f16)v[0]; bb[1]=(f16)v[1]; bb[2]=(f16)v[2]; bb[3]=(f16)v[3];
            *reinterpret_cast<f16x4*>((char*)Bs + swz(row, c4 * 8)) = bb;
        }
        __syncthreads();
        int rb = w * 32 + l31;
#pragma unroll
        for (int k4 = 0; k4 < 4; k4++) {
            f16x8 bfr = *reinterpret_cast<const f16x8*>((char*)Bs + swz(rb, k4 * 32 + half * 16));
            acc[c] = __builtin_amdgcn_mfma_f32_32x32x16_f16(afr[k4], bfr, acc[c], 0, 0, 0);
        }
    }

    // epilogue: mask (from LDS), exp (no max needed: scores bounded, masked -> 0)
    float rsum[16];
#pragma unroll
    for (int r = 0; r < 16; r++) rsum[r] = 0.f;
#pragma unroll
    for (int c = 0; c < 4; c++) {
        int kcol = c * 128 + w * 32 + l31;
#pragma unroll
        for (int r = 0; r < 16; r++) {
            int qrow = (r & 3) + 8 * (r >> 2) + 4 * half;
            int mk = Ms[qrow * 512 + kcol];
            float e = mk ? __expf(acc[c][r] * 0.125f) : 0.f;
            acc[c][r] = e;
            rsum[r] += e;
        }
    }
    // row-sum: tree within 32-lane half (rows are half-local), then cross-wave via LDS
#pragma unroll
    for (int d = 1; d < 32; d <<= 1)
#pragma unroll
        for (int r = 0; r < 16; r++) rsum[r] += __shfl_xor(rsum[r], d);
    if (l31 == 0) {
#pragma unroll
        for (int r = 0; r < 16; r++) {
            int qrow = (r & 3) + 8 * (r >> 2) + 4 * half;
            red[w][qrow] = rsum[r];
        }
    }
    __syncthreads();
    float inv[16];
#pragma unroll
    for (int r = 0; r < 16; r++) {
        int qrow = (r & 3) + 8 * (r >> 2) + 4 * half;
        float s = red[0][qrow] + red[1][qrow] + red[2][qrow] + red[3][qrow];
        inv[r] = 1.0f / s;
    }
    float* P = dout + OUT0 + (size_t)m * PSZ + (size_t)bh * MSZ + (size_t)(qt * 32) * SEQ;
#pragma unroll
    for (int c = 0; c < 4; c++) {
        int kcol = c * 128 + w * 32 + l31;
#pragma unroll
        for (int r = 0; r < 16; r++) {
            int qrow = (r & 3) + 8 * (r >> 2) + 4 * half;
            // non-temporal: 492 MB write stream must not evict hot mask/B panels
            __builtin_nontemporal_store(acc[c][r] * inv[r], &P[(size_t)qrow * SEQ + kcol]);
        }
    }
}

// ---------------- V transpose: [bh][k][d] fp32 -> [bh][d][k] f16 ----------------
__global__ __launch_bounds__(256) void vtrans(const float* __restrict__ v, f16* __restrict__ vt)
{
    __shared__ float t[128][65];
    const int tid = threadIdx.x;
    const int bid = blockIdx.x;
    const int b = bid & 7;
    int r = bid >> 3;                 // 0..47
    const int ck = r & 3;
    const int h  = r >> 2;            // 0..11
    const int bh = b * 12 + h;
    const float* Vg = v + ((size_t)bh * SEQ + ck * 128) * DIM;
#pragma unroll
    for (int i = 0; i < 8; i++) {
        int g = tid + 256 * i; int row = g >> 4, c4 = g & 15;
        f32x4 vv = *reinterpret_cast<const f32x4*>(Vg + row * 64 + c4 * 4);
        t[row][c4*4+0] = vv[0]; t[row][c4*4+1] = vv[1];
        t[row][c4*4+2] = vv[2]; t[row][c4*4+3] = vv[3];
    }
    __syncthreads();
    f16* Og = vt + (size_t)bh * DIM * SEQ + ck * 128;
#pragma unroll
    for (int i = 0; i < 16; i++) {
        int p = tid + 256 * i; int d = p >> 6; int j = (p & 63) * 2;
        f16x2 o; o[0] = (f16)t[j][d]; o[1] = (f16)t[j + 1][d];
        *reinterpret_cast<f16x2*>(Og + (size_t)d * SEQ + j) = o;
    }
}

// ---------------- PV via MFMA (reads p_attn from dout, Vt from ws) ----------------
__global__ __launch_bounds__(256) void pv_mfma(const float* __restrict__ dout,
                                               const f16* __restrict__ vt,
                                               float* __restrict__ out)
{
    __shared__ __align__(16) f16 Ps[64 * 64];
    __shared__ __align__(16) f16 Vs[64 * 64];
    const int tid = threadIdx.x;
    const int bid = blockIdx.x;
    const int b = bid & 7;
    int r = bid >> 3;                 // 0..95
    const int qt = r & 7;
    const int h  = r >> 3;            // 0..11
    const int bh = b * 12 + h;
    const int w = tid >> 6, lane = tid & 63, l31 = lane & 31, half = lane >> 5;
    const int wr = w >> 1, wc = w & 1;

    const float* Pg = dout + OUT0 + (size_t)bh * MSZ + (size_t)(qt * 64) * SEQ;
    const f16* Vg = vt + (size_t)bh * DIM * SEQ;

    f32x16 acc;
#pragma unroll
    for (int i = 0; i < 16; i++) acc[i] = 0.f;

    for (int c = 0; c < 8; c++) {
        __syncthreads();
#pragma unroll
        for (int i = 0; i < 4; i++) {            // P chunk [64 q][64 kv], nt load (stream)
            int g = tid + 256 * i; int row = g >> 4, c4 = g & 15;
            f32x4 v = __builtin_nontemporal_load(
                reinterpret_cast<const f32x4*>(Pg + (size_t)row * SEQ + c * 64 + c4 * 4));
            f16x4 bb; bb[0]=(f16)v[0]; bb[1]=(f16)v[1]; bb[2]=(f16)v[2]; bb[3]=(f16)v[3];
            *reinterpret_cast<f16x4*>((char*)Ps + swz(row, c4 * 8)) = bb;
        }
#pragma unroll
        for (int i = 0; i < 2; i++) {            // Vt chunk [64 d][64 kv]
            int g = tid + 256 * i; int row = g >> 3, c8 = g & 7;
            f16x8 v = *reinterpret_cast<const f16x8*>(Vg + (size_t)row * SEQ + c * 64 + c8 * 8);
            *reinterpret_cast<f16x8*>((char*)Vs + swz(row, c8 * 16)) = v;
        }
        __syncthreads();
        int qr = wr * 32 + l31, dr = wc * 32 + l31;
#pragma unroll
        for (int k4 = 0; k4 < 4; k4++) {
            int co = k4 * 32 + half * 16;
            f16x8 a  = *reinterpret_cast<const f16x8*>((char*)Ps + swz(qr, co));
            f16x8 bb = *reinterpret_cast<const f16x8*>((char*)Vs + swz(dr, co));
            acc = __builtin_amdgcn_mfma_f32_32x32x16_f16(a, bb, acc, 0, 0, 0);
        }
    }
    float* og = out + ((size_t)bh * SEQ + qt * 64 + wr * 32) * DIM + wc * 32;
#pragma unroll
    for (int r2 = 0; r2 < 16; r2++) {
        int qrow = (r2 & 3) + 8 * (r2 >> 2) + 4 * half;
        og[(size_t)qrow * DIM + l31] = acc[r2];
    }
}

// ---------------- PV vector fallback (if ws too small for Vt) ----------------
__global__ __launch_bounds__(256) void pv_vec(const float* __restrict__ dout,
                                              const float* __restrict__ v,
                                              float* __restrict__ out)
{
    __shared__ float Vs[128][64];
    const int tid = threadIdx.x;
    const int bid = blockIdx.x;
    const int b = bid & 7;
    int r = bid >> 3;
    const int qt = r & 7;
    const int h  = r >> 3;
    const int bh = b * 12 + h;
    float accv[16];
#pragma unroll
    for (int j = 0; j < 16; j++) accv[j] = 0.f;
    const float* Prow = dout + OUT0 + ((size_t)bh * SEQ + qt * 64 + (tid >> 2)) * SEQ;
    const int dbase = (tid & 3) * 16;
    for (int ck = 0; ck < 4; ck++) {
        __syncthreads();
        const float* Vg = v + ((size_t)bh * SEQ + ck * 128) * DIM;
#pragma unroll
        for (int i = 0; i < 8; i++) {
            int g = tid + 256 * i; int row = g >> 4, c4 = g & 15;
            f32x4 vv = *reinterpret_cast<const f32x4*>(Vg + row * 64 + c4 * 4);
            Vs[row][c4*4+0] = vv[0]; Vs[row][c4*4+1] = vv[1];
            Vs[row][c4*4+2] = vv[2]; Vs[row][c4*4+3] = vv[3];
        }
        __syncthreads();
        for (int kv = 0; kv < 128; kv++) {
            float p = Prow[ck * 128 + kv];
#pragma unroll
            for (int j = 0; j < 16; j++) accv[j] += p * Vs[kv][dbase + j];
        }
    }
    float* og = out + ((size_t)bh * SEQ + qt * 64 + (tid >> 2)) * DIM + dbase;
#pragma unroll
    for (int j = 0; j < 16; j++) og[j] = accv[j];
}

extern "C" void kernel_launch(void* const* d_in, const int* in_sizes, int n_in,
                              void* d_out, int out_size, void* d_ws, size_t ws_size,
                              hipStream_t stream) {
    const float* q_  = (const float*)d_in[0];
    const float* k_  = (const float*)d_in[1];
    const float* v_  = (const float*)d_in[2];
    const int*   msk = (const int*)d_in[3];
    const float* xo1 = (const float*)d_in[4];
    const float* xo2 = (const float*)d_in[5];
    const float* xp1 = (const float*)d_in[6];
    const float* xp2 = (const float*)d_in[7];
    float* out = (float*)d_out;

    scores_softmax<<<5 * NBH * 16, 256, 0, stream>>>(q_, k_, xo1, xo2, xp1, xp2, msk, out);

    const size_t need = (size_t)NBH * DIM * SEQ * sizeof(f16);
    if (ws_size >= need) {
        f16* vt = (f16*)d_ws;
        vtrans<<<NBH * 4, 256, 0, stream>>>(v_, vt);
        pv_mfma<<<NBH * 8, 256, 0, stream>>>(out, vt, out);
    } else {
        pv_vec<<<NBH * 8, 256, 0, stream>>>(out, v_, out);
    }
}

// Round 9
// 634.708 us; speedup vs baseline: 1.1243x; 1.0853x over previous
//
#include <hip/hip_runtime.h>
#include <hip/hip_bf16.h>

typedef _Float16 f16;
typedef f16 f16x2 __attribute__((ext_vector_type(2)));
typedef f16 f16x4 __attribute__((ext_vector_type(4)));
typedef f16 f16x8 __attribute__((ext_vector_type(8)));
typedef float f32x4 __attribute__((ext_vector_type(4)));
typedef float f32x16 __attribute__((ext_vector_type(16)));
typedef int i32x4 __attribute__((ext_vector_type(4)));
typedef unsigned char u8;
typedef u8 u8x4 __attribute__((ext_vector_type(4)));

#define SEQ 512
#define DIM 64
#define NBH 96
#define OUT0 3145728          // 8*12*512*64
#define PSZ  25165824         // 8*12*512*512
#define MSZ  262144           // 512*512

__device__ __forceinline__ int swz(int row, int colByte) {
    return row * 128 + (colByte ^ ((row & 7) << 4));
}

// ================= scores + masked softmax, all 5 matrices per block =================
// Block = (bh, 64-row q-chunk). Grid 768 = 3 blocks/CU exactly.
// B matrices (k_, xo2, xp2) each loaded ONCE into LDS (full 512x64 f16) and reused
// for the m's that need them (order m = 0, 1, 3, 2, 4). A (3 sources) + mask staged once.
// Reuse is structural (LDS), not cache-dependent: 910 MB total vs 2.0 GB before.
__global__ __launch_bounds__(512, 2) void scores5(
    const float* __restrict__ q_, const float* __restrict__ k_,
    const float* __restrict__ xo1, const float* __restrict__ xo2,
    const float* __restrict__ xp1, const float* __restrict__ xp2,
    const int* __restrict__ mask, float* __restrict__ dout)
{
    __shared__ __align__(16) f16 Bs[SEQ * DIM];      // 64 KB, swizzled
    __shared__ __align__(16) u8  Ms[64 * SEQ];       // 32 KB
    __shared__ __align__(16) f16 As[3 * 64 * DIM];   // 24 KB, swizzled per source
    __shared__ float red[2][4][32];                  // 1 KB

    const int tid = threadIdx.x;
    const int bid = blockIdx.x;
    const int qc  = bid / NBH;        // 0..7  (96 apart -> same-(b,h) chunks share XCD)
    const int bh  = bid % NBH;
    const int b   = bh / 12;

    const int w = tid >> 6, lane = tid & 63, l31 = lane & 31, half = lane >> 5;
    const int qsub = w & 1;           // which 32-row half of the 64-row chunk
    const int kq   = w >> 1;          // which 128-col quadrant of the 512 k-cols

    // ---- stage mask tile [64 q][512 k] -> u8 LDS (read ONCE, reused by all 5 m)
    const int* mrow = mask + (size_t)b * MSZ + (size_t)(qc * 64) * SEQ;
#pragma unroll
    for (int i = 0; i < 16; i++) {
        int g = tid + 512 * i;        // i32x4 index, 0..8191
        i32x4 mv = *reinterpret_cast<const i32x4*>(mrow + g * 4);
        u8x4 pk;
        pk[0] = (u8)(mv[0] != 0); pk[1] = (u8)(mv[1] != 0);
        pk[2] = (u8)(mv[2] != 0); pk[3] = (u8)(mv[3] != 0);
        *reinterpret_cast<u8x4*>(&Ms[g * 4]) = pk;
    }

    // ---- stage A tiles: 3 sources x [64 q][64 d] -> f16 LDS (swizzled)
    {
        const float* srcs[3] = { q_, xo1, xp1 };
#pragma unroll
        for (int s = 0; s < 3; s++) {
            const float* Ag = srcs[s] + ((size_t)bh * SEQ + qc * 64) * DIM;
#pragma unroll
            for (int i = 0; i < 2; i++) {
                int g = tid + 512 * i; int row = g >> 4, c4 = g & 15;
                f32x4 v = *reinterpret_cast<const f32x4*>(Ag + row * 64 + c4 * 4);
                f16x4 hv; hv[0]=(f16)v[0]; hv[1]=(f16)v[1]; hv[2]=(f16)v[2]; hv[3]=(f16)v[3];
                *reinterpret_cast<f16x4*>((char*)As + s * 8192 + swz(row, c4 * 8)) = hv;
            }
        }
    }
    __syncthreads();

    // ---- A fragments in registers (held across all 5 m): 3 x 4 x f16x8 = 48 VGPR
    f16x8 af0[4], af1[4], af2[4];
#pragma unroll
    for (int k4 = 0; k4 < 4; k4++) {
        af0[k4] = *reinterpret_cast<const f16x8*>((char*)As + 0     + swz(qsub*32 + l31, k4*32 + half*16));
        af1[k4] = *reinterpret_cast<const f16x8*>((char*)As + 8192  + swz(qsub*32 + l31, k4*32 + half*16));
        af2[k4] = *reinterpret_cast<const f16x8*>((char*)As + 16384 + swz(qsub*32 + l31, k4*32 + half*16));
    }

    auto step = [&](const f16x8 (&afr)[4], int mout, const float* bsrc) {
        if (bsrc) {                   // load a new B matrix [512 k][64 d] -> f16 LDS
            __syncthreads();          // prior MFMA reads of Bs done
            const float* Bg = bsrc + (size_t)bh * SEQ * DIM;
#pragma unroll
            for (int i = 0; i < 16; i++) {
                int g = tid + 512 * i; int row = g >> 4, c4 = g & 15;
                f32x4 v = *reinterpret_cast<const f32x4*>(Bg + row * 64 + c4 * 4);
                f16x4 hv; hv[0]=(f16)v[0]; hv[1]=(f16)v[1]; hv[2]=(f16)v[2]; hv[3]=(f16)v[3];
                *reinterpret_cast<f16x4*>((char*)Bs + swz(row, c4 * 8)) = hv;
            }
        }
        __syncthreads();              // Bs ready; previous step's red reads done

        f32x16 acc[4];
#pragma unroll
        for (int c2 = 0; c2 < 4; c2++) {
#pragma unroll
            for (int i = 0; i < 16; i++) acc[c2][i] = 0.f;
#pragma unroll
            for (int k4 = 0; k4 < 4; k4++) {
                f16x8 bf = *reinterpret_cast<const f16x8*>(
                    (char*)Bs + swz(kq * 128 + c2 * 32 + l31, k4 * 32 + half * 16));
                acc[c2] = __builtin_amdgcn_mfma_f32_32x32x16_f16(afr[k4], bf, acc[c2], 0, 0, 0);
            }
        }

        // epilogue: mask (LDS u8), exp (no max-subtract: scores bounded; masked -> exactly 0)
        float rsum[16];
#pragma unroll
        for (int r = 0; r < 16; r++) rsum[r] = 0.f;
#pragma unroll
        for (int c2 = 0; c2 < 4; c2++) {
            int kcol = kq * 128 + c2 * 32 + l31;
#pragma unroll
            for (int r = 0; r < 16; r++) {
                int qrow = (r & 3) + 8 * (r >> 2) + 4 * half;
                float e = Ms[(qsub * 32 + qrow) * SEQ + kcol] ? __expf(acc[c2][r] * 0.125f) : 0.f;
                acc[c2][r] = e;
                rsum[r] += e;
            }
        }
        // row-sum tree within 32-lane half (rows are half-local), cross-wave via LDS
#pragma unroll
        for (int d = 1; d < 32; d <<= 1)
#pragma unroll
            for (int r = 0; r < 16; r++) rsum[r] += __shfl_xor(rsum[r], d);
        if (l31 == 0) {
#pragma unroll
            for (int r = 0; r < 16; r++) {
                int qrow = (r & 3) + 8 * (r >> 2) + 4 * half;
                red[qsub][kq][qrow] = rsum[r];
            }
        }
        __syncthreads();              // red ready
        float inv[16];
#pragma unroll
        for (int r = 0; r < 16; r++) {
            int qrow = (r & 3) + 8 * (r >> 2) + 4 * half;
            inv[r] = 1.0f / (red[qsub][0][qrow] + red[qsub][1][qrow] +
                             red[qsub][2][qrow] + red[qsub][3][qrow]);
        }
        float* P = dout + OUT0 + (size_t)mout * PSZ + (size_t)bh * MSZ + (size_t)(qc * 64) * SEQ;
#pragma unroll
        for (int c2 = 0; c2 < 4; c2++) {
            int kcol = kq * 128 + c2 * 32 + l31;
#pragma unroll
            for (int r = 0; r < 16; r++) {
                int qrow = (r & 3) + 8 * (r >> 2) + 4 * half;
                // nt: the 480 MB P stream must not thrash caches
                __builtin_nontemporal_store(acc[c2][r] * inv[r],
                                            &P[(size_t)(qsub * 32 + qrow) * SEQ + kcol]);
            }
        }
    };

    step(af0, 0, k_);        // load B = k
    step(af1, 1, xo2);       // load B = xo2
    step(af2, 3, nullptr);   //   reuse xo2
    step(af1, 2, xp2);       // load B = xp2
    step(af2, 4, nullptr);   //   reuse xp2
}

// ---------------- V transpose: [bh][k][d] fp32 -> [bh][d][k] f16 ----------------
__global__ __launch_bounds__(256) void vtrans(const float* __restrict__ v, f16* __restrict__ vt)
{
    __shared__ float t[128][65];
    const int tid = threadIdx.x;
    const int bid = blockIdx.x;
    const int b = bid & 7;
    int r = bid >> 3;                 // 0..47
    const int ck = r & 3;
    const int h  = r >> 2;            // 0..11
    const int bh = b * 12 + h;
    const float* Vg = v + ((size_t)bh * SEQ + ck * 128) * DIM;
#pragma unroll
    for (int i = 0; i < 8; i++) {
        int g = tid + 256 * i; int row = g >> 4, c4 = g & 15;
        f32x4 vv = *reinterpret_cast<const f32x4*>(Vg + row * 64 + c4 * 4);
        t[row][c4*4+0] = vv[0]; t[row][c4*4+1] = vv[1];
        t[row][c4*4+2] = vv[2]; t[row][c4*4+3] = vv[3];
    }
    __syncthreads();
    f16* Og = vt + (size_t)bh * DIM * SEQ + ck * 128;
#pragma unroll
    for (int i = 0; i < 16; i++) {
        int p = tid + 256 * i; int d = p >> 6; int j = (p & 63) * 2;
        f16x2 o; o[0] = (f16)t[j][d]; o[1] = (f16)t[j + 1][d];
        *reinterpret_cast<f16x2*>(Og + (size_t)d * SEQ + j) = o;
    }
}

// ---------------- PV via MFMA (reads p_attn from dout, Vt from ws) ----------------
__global__ __launch_bounds__(256) void pv_mfma(const float* __restrict__ dout,
                                               const f16* __restrict__ vt,
                                               float* __restrict__ out)
{
    __shared__ __align__(16) f16 Ps[64 * 64];
    __shared__ __align__(16) f16 Vs[64 * 64];
    const int tid = threadIdx.x;
    const int bid = blockIdx.x;
    const int b = bid & 7;
    int r = bid >> 3;                 // 0..95
    const int qt = r & 7;
    const int h  = r >> 3;            // 0..11
    const int bh = b * 12 + h;
    const int w = tid >> 6, lane = tid & 63, l31 = lane & 31, half = lane >> 5;
    const int wr = w >> 1, wc = w & 1;

    const float* Pg = dout + OUT0 + (size_t)bh * MSZ + (size_t)(qt * 64) * SEQ;
    const f16* Vg = vt + (size_t)bh * DIM * SEQ;

    f32x16 acc;
#pragma unroll
    for (int i = 0; i < 16; i++) acc[i] = 0.f;

    for (int c = 0; c < 8; c++) {
        __syncthreads();
#pragma unroll
        for (int i = 0; i < 4; i++) {            // P chunk [64 q][64 kv], nt load (stream)
            int g = tid + 256 * i; int row = g >> 4, c4 = g & 15;
            f32x4 v = __builtin_nontemporal_load(
                reinterpret_cast<const f32x4*>(Pg + (size_t)row * SEQ + c * 64 + c4 * 4));
            f16x4 bb; bb[0]=(f16)v[0]; bb[1]=(f16)v[1]; bb[2]=(f16)v[2]; bb[3]=(f16)v[3];
            *reinterpret_cast<f16x4*>((char*)Ps + swz(row, c4 * 8)) = bb;
        }
#pragma unroll
        for (int i = 0; i < 2; i++) {            // Vt chunk [64 d][64 kv]
            int g = tid + 256 * i; int row = g >> 3, c8 = g & 7;
            f16x8 v = *reinterpret_cast<const f16x8*>(Vg + (size_t)row * SEQ + c * 64 + c8 * 8);
            *reinterpret_cast<f16x8*>((char*)Vs + swz(row, c8 * 16)) = v;
        }
        __syncthreads();
        int qr = wr * 32 + l31, dr = wc * 32 + l31;
#pragma unroll
        for (int k4 = 0; k4 < 4; k4++) {
            int co = k4 * 32 + half * 16;
            f16x8 a  = *reinterpret_cast<const f16x8*>((char*)Ps + swz(qr, co));
            f16x8 bb = *reinterpret_cast<const f16x8*>((char*)Vs + swz(dr, co));
            acc = __builtin_amdgcn_mfma_f32_32x32x16_f16(a, bb, acc, 0, 0, 0);
        }
    }
    float* og = out + ((size_t)bh * SEQ + qt * 64 + wr * 32) * DIM + wc * 32;
#pragma unroll
    for (int r2 = 0; r2 < 16; r2++) {
        int qrow = (r2 & 3) + 8 * (r2 >> 2) + 4 * half;
        og[(size_t)qrow * DIM + l31] = acc[r2];
    }
}

// ---------------- PV vector fallback (if ws too small for Vt) ----------------
__global__ __launch_bounds__(256) void pv_vec(const float* __restrict__ dout,
                                              const float* __restrict__ v,
                                              float* __restrict__ out)
{
    __shared__ float Vs[128][64];
    const int tid = threadIdx.x;
    const int bid = blockIdx.x;
    const int b = bid & 7;
    int r = bid >> 3;
    const int qt = r & 7;
    const int h  = r >> 3;
    const int bh = b * 12 + h;
    float accv[16];
#pragma unroll
    for (int j = 0; j < 16; j++) accv[j] = 0.f;
    const float* Prow = dout + OUT0 + ((size_t)bh * SEQ + qt * 64 + (tid >> 2)) * SEQ;
    const int dbase = (tid & 3) * 16;
    for (int ck = 0; ck < 4; ck++) {
        __syncthreads();
        const float* Vg = v + ((size_t)bh * SEQ + ck * 128) * DIM;
#pragma unroll
        for (int i = 0; i < 8; i++) {
            int g = tid + 256 * i; int row = g >> 4, c4 = g & 15;
            f32x4 vv = *reinterpret_cast<const f32x4*>(Vg + row * 64 + c4 * 4);
            Vs[row][c4*4+0] = vv[0]; Vs[row][c4*4+1] = vv[1];
            Vs[row][c4*4+2] = vv[2]; Vs[row][c4*4+3] = vv[3];
        }
        __syncthreads();
        for (int kv = 0; kv < 128; kv++) {
            float p = Prow[ck * 128 + kv];
#pragma unroll
            for (int j = 0; j < 16; j++) accv[j] += p * Vs[kv][dbase + j];
        }
    }
    float* og = out + ((size_t)bh * SEQ + qt * 64 + (tid >> 2)) * DIM + dbase;
#pragma unroll
    for (int j = 0; j < 16; j++) og[j] = accv[j];
}

extern "C" void kernel_launch(void* const* d_in, const int* in_sizes, int n_in,
                              void* d_out, int out_size, void* d_ws, size_t ws_size,
                              hipStream_t stream) {
    const float* q_  = (const float*)d_in[0];
    const float* k_  = (const float*)d_in[1];
    const float* v_  = (const float*)d_in[2];
    const int*   msk = (const int*)d_in[3];
    const float* xo1 = (const float*)d_in[4];
    const float* xo2 = (const float*)d_in[5];
    const float* xp1 = (const float*)d_in[6];
    const float* xp2 = (const float*)d_in[7];
    float* out = (float*)d_out;

    scores5<<<8 * NBH, 512, 0, stream>>>(q_, k_, xo1, xo2, xp1, xp2, msk, out);

    const size_t need = (size_t)NBH * DIM * SEQ * sizeof(f16);
    if (ws_size >= need) {
        f16* vt = (f16*)d_ws;
        vtrans<<<NBH * 4, 256, 0, stream>>>(v_, vt);
        pv_mfma<<<NBH * 8, 256, 0, stream>>>(out, vt, out);
    } else {
        pv_vec<<<NBH * 8, 256, 0, stream>>>(out, v_, out);
    }
}